// Round 3
// baseline (116.262 us; speedup 1.0000x reference)
//
#include <hip/hip_runtime.h>

#define D 32
#define T 2049
#define NH 2

// ---------------------------------------------------------------------------
// Kernel A: for one layer, compute sign signatures of U = B@Z and W = C@Z.
// Signature for column t: bit k = (U[k,t] > 0), bit 32 = any(U[k,t] == 0).
// attn[l,j] = 1  iff  sigU[l] == sigW[j] and neither has the zero flag.
// Block = 256 threads = 8 columns x 32 rows; one wave covers 2 columns, so a
// single 64-lane __ballot yields both columns' signatures.
// ---------------------------------------------------------------------------
__global__ __launch_bounds__(256) void sig_kernel(
    const float* __restrict__ Z,          // (D, T) row-major
    const float* __restrict__ allparam,   // (2, 2, 3, 32, 32)
    int layer,
    unsigned long long* __restrict__ sigU, // (NH, T)
    unsigned long long* __restrict__ sigW) // (NH, T)
{
    const int h   = blockIdx.y;
    const int t0  = blockIdx.x * 8;
    const int tid = threadIdx.x;

    __shared__ float Bs[32][32];
    __shared__ float Cs[32][32];
    __shared__ float Zs[32][8];

    const float* Bp = allparam + (((layer * NH + h) * 3) + 1) * 1024;
    const float* Cp = allparam + (((layer * NH + h) * 3) + 2) * 1024;
    #pragma unroll
    for (int i = 0; i < 4; ++i) {
        ((float*)Bs)[tid + 256 * i] = Bp[tid + 256 * i];
        ((float*)Cs)[tid + 256 * i] = Cp[tid + 256 * i];
    }
    {
        int d = tid >> 3, c = tid & 7;
        int t = t0 + c; if (t >= T) t = T - 1;   // clamp; keeps all lanes active
        Zs[d][c] = Z[d * T + t];
    }
    __syncthreads();

    const int c = tid >> 5;   // column within block (0..7)
    const int k = tid & 31;   // row
    float u = 0.f, w = 0.f;
    #pragma unroll
    for (int d = 0; d < 32; ++d) {
        float z = Zs[d][c];
        u += Bs[k][d] * z;
        w += Cs[k][d] * z;
    }

    unsigned long long pu = __ballot(u > 0.0f);
    unsigned long long zu = __ballot(u == 0.0f);
    unsigned long long pw = __ballot(w > 0.0f);
    unsigned long long zw = __ballot(w == 0.0f);

    const int wid = tid & 63;
    const int t = t0 + c;
    if ((wid == 0 || wid == 32) && t < T) {
        const int sh = (wid == 0) ? 0 : 32;
        unsigned long long su = (unsigned int)(pu >> sh);
        if ((unsigned int)(zu >> sh)) su |= (1ull << 32);
        unsigned long long sw = (unsigned int)(pw >> sh);
        if ((unsigned int)(zw >> sh)) sw |= (1ull << 32);
        sigU[h * T + t] = su;
        sigW[h * T + t] = sw;
    }
}

// ---------------------------------------------------------------------------
// Kernel B: one wave per output column j. For each head, scan sigU[0..2047]
// (source column T-1 is masked out by M) against sigW[j]; on the (rare)
// match, recompute key[:,l] = V @ Z[:,l] on demand and accumulate.
// Writes Zout[:,j] = Zin[:,j] + sum of matched key columns (both heads).
// ---------------------------------------------------------------------------
__global__ __launch_bounds__(64) void attn_kernel(
    const float* __restrict__ Zin,
    const float* __restrict__ allparam,
    int layer,
    const unsigned long long* __restrict__ sigU,
    const unsigned long long* __restrict__ sigW,
    float* __restrict__ Zout)
{
    const int j    = blockIdx.x;
    const int lane = threadIdx.x;
    const int k    = lane & 31;

    float acc = 0.f;
    #pragma unroll
    for (int h = 0; h < NH; ++h) {
        const unsigned long long wv = sigW[h * T + j];
        if (wv >> 32) continue;  // W column has a zero -> whole attn column 0
        const float* V = allparam + ((layer * NH + h) * 3 + 0) * 1024;
        const unsigned long long* su = sigU + h * T;
        for (int it = 0; it < 32; ++it) {          // 32 * 64 = 2048 sources
            const int l = it * 64 + lane;
            const bool m = (su[l] == wv);
            unsigned long long mask = __ballot(m);
            while (mask) {                          // wave-uniform rare path
                const int b = __builtin_ctzll(mask);
                mask &= mask - 1;
                const int lm = it * 64 + b;
                float kv = 0.f;
                #pragma unroll
                for (int d = 0; d < 32; ++d)
                    kv += V[k * 32 + d] * Zin[d * T + lm];
                acc += kv;
            }
        }
    }
    if (lane < 32) {
        Zout[k * T + j] = Zin[k * T + j] + acc;
    }
}

extern "C" void kernel_launch(void* const* d_in, const int* in_sizes, int n_in,
                              void* d_out, int out_size, void* d_ws, size_t ws_size,
                              hipStream_t stream) {
    const float* Z        = (const float*)d_in[0];   // (32, 2049) f32
    const float* allparam = (const float*)d_in[1];   // (2,2,3,32,32) f32
    float* out            = (float*)d_out;           // (32, 2049) f32

    // workspace layout
    float* Zmid = (float*)d_ws;                                   // 32*2049 f32
    size_t sig_off = ((size_t)D * T * sizeof(float) + 255) & ~(size_t)255;
    unsigned long long* sigU = (unsigned long long*)((char*)d_ws + sig_off);
    unsigned long long* sigW = sigU + (size_t)NH * T;             // each NH*T u64

    dim3 gA((T + 7) / 8, NH);   // 257 x 2 blocks

    // layer 0: Z -> Zmid
    sig_kernel<<<gA, 256, 0, stream>>>(Z, allparam, 0, sigU, sigW);
    attn_kernel<<<T, 64, 0, stream>>>(Z, allparam, 0, sigU, sigW, Zmid);

    // layer 1: Zmid -> out
    sig_kernel<<<gA, 256, 0, stream>>>(Zmid, allparam, 1, sigU, sigW);
    attn_kernel<<<T, 64, 0, stream>>>(Zmid, allparam, 1, sigU, sigW, out);
}